// Round 9
// baseline (397.207 us; speedup 1.0000x reference)
//
#include <hip/hip_runtime.h>

// ---------------------------------------------------------------------------
// GAT encoder, 2 layers, MI355X — round 9.
// Dtype-adaptive (probe: f32-vs-bf16 floats, i64-vs-i32 indices).
// bf16 internal, f32 accumulation, direct-sum softmax (logits bounded).
// CSR: bucket sort (pass1 fused w/ prep; pass2 fused w/ gemm1).
// NEW (r8 lesson: node1 passes are dual-bound ~69% VALU / ~75% fabric):
//   wk1/wk2 precompute per-edge unnormalized p (bf16, packed with src) and
//   per-node 1/l. Aggregation passes shrink to load-gather-FMA only:
//   node1 passes: 4 edges/wave (16 lanes x uint4 = 128ch), p selected from
//   packed stream; normalize once in epilogue via precomputed inv_l.
//   node2: same, 4ch/lane uint2 gathers, 4B/edge packed {src16|p_bf16}.
// 9 dispatches: probe, prep+bucket, gemm1+pass2, wk1, pass0, pass1,
//               gemm2, wk2, node2.
// ---------------------------------------------------------------------------

typedef __attribute__((ext_vector_type(8))) short short8;
typedef __attribute__((ext_vector_type(4))) float floatx4;

#define FIN 256
#define H1 4
#define CH 64
#define CAP 16384   // bucket capacity (avg fill 8.4K, sigma ~92)

__device__ __forceinline__ float bf2f(ushort u) {
    union { unsigned int i; float f; } v; v.i = ((unsigned int)u) << 16; return v.f;
}
__device__ __forceinline__ ushort f2bf(float f) {
    union { float f; unsigned int i; } v; v.f = f;
    unsigned int r = v.i + 0x7fffu + ((v.i >> 16) & 1u);  // RNE
    return (ushort)(r >> 16);
}
__device__ __forceinline__ float bits2f(unsigned int b) {
    union { unsigned int i; float f; } v; v.i = b; return v.f;
}
__device__ __forceinline__ float load_in(const void* p, int i, int f) {
    return f ? ((const float*)p)[i] : bf2f(((const ushort*)p)[i]);
}
__device__ __forceinline__ int load_idx(const void* p, long long i, int f64) {
    return f64 ? (int)((const long long*)p)[i] : ((const int*)p)[i];
}

// ---- dtype probe + bcnt zero ----------------------------------------------
__global__ __launch_bounds__(256) void probe_kernel(const ushort* __restrict__ x,
                                                    const int* __restrict__ ei,
                                                    int* __restrict__ flags,
                                                    int* __restrict__ bcnt) {
    __shared__ int s_nan, s_odd;
    int t = threadIdx.x;
    bcnt[t] = 0;
    if (t == 0) { s_nan = 0; s_odd = 0; }
    __syncthreads();
    int nanc = 0, oddc = 0;
    for (int i = t; i < 16384; i += 256) {
        ushort u = x[i];
        if (((u >> 7) & 0xFF) == 0xFF) nanc++;
    }
    for (int i = t; i < 2048; i += 256)
        if (ei[2 * i + 1] != 0) oddc++;
    if (nanc) atomicAdd(&s_nan, nanc);
    if (oddc) atomicAdd(&s_odd, oddc);
    __syncthreads();
    if (t == 0) {
        flags[0] = (s_nan >= 2) ? 1 : 0;  // 1 = floats are f32
        flags[1] = (s_odd == 0) ? 1 : 0;  // 1 = indices are int64
    }
}

// ---- fused: x convert (8/thr) | W transposes | CSR bucket pass 1 -----------
__global__ __launch_bounds__(256) void prep_bucket_kernel(
        const void* __restrict__ x, const void* __restrict__ W1,
        const void* __restrict__ W2, ushort* __restrict__ xb,
        ushort* __restrict__ Wt1, ushort* __restrict__ Wt2,
        const void* __restrict__ ei, int* __restrict__ bcnt,
        unsigned int* __restrict__ buckets,
        int E, int Etot, int Nn, const int* __restrict__ flags,
        int PB_conv, int PB_tr_end) {
    __shared__ int lcnt[256], lbase[256], lcur[256];
    int bid = blockIdx.x, t = threadIdx.x;
    int f = flags[0];
    if (bid < PB_conv) {                       // ---- x -> bf16, 8 elem/thread
        int i0 = bid * 2048 + t * 8;
        if (f) {
            float4 v0 = ((const float4*)x)[i0 / 4];
            float4 v1 = ((const float4*)x)[i0 / 4 + 1];
            ushort4 o0, o1;
            o0.x = f2bf(v0.x); o0.y = f2bf(v0.y); o0.z = f2bf(v0.z); o0.w = f2bf(v0.w);
            o1.x = f2bf(v1.x); o1.y = f2bf(v1.y); o1.z = f2bf(v1.z); o1.w = f2bf(v1.w);
            *(ushort4*)(xb + i0) = o0;
            *(ushort4*)(xb + i0 + 4) = o1;
        } else {
            *(uint4*)(xb + i0) = ((const uint4*)x)[i0 / 8];
        }
        return;
    }
    if (bid < PB_tr_end) {                     // ---- W1^T, W2^T
        int j = (bid - PB_conv) * 256 + t;
        if (j < FIN * FIN) {
            int n = j / FIN, k = j % FIN;
            Wt1[j] = f2bf(load_in(W1, k * FIN + n, f));
        } else {
            int jj = j - FIN * FIN;
            int n = jj / FIN, k = jj % FIN;
            Wt2[jj] = f2bf(load_in(W2, k * CH + n, f));
        }
        return;
    }
    // ---- CSR pass 1: bucket partition, 16 edges/thread (4096/block)
    lcnt[t] = 0; lcur[t] = 0;
    __syncthreads();
    int f64 = flags[1];
    int base = (bid - PB_tr_end) * 4096 + t;
    unsigned int val[16]; int bk[16]; bool ok[16];
#pragma unroll
    for (int j = 0; j < 16; ++j) {
        int e = base + j * 256;
        ok[j] = e < Etot;
        bk[j] = 0; val[j] = 0;
        if (ok[j]) {
            int s, d;
            if (e < E) {
                s = load_idx(ei, e, f64);
                d = load_idx(ei, (long long)E + e, f64);
            } else {
                s = d = e - E;   // self-loops appended
            }
            s = min(max(s, 0), Nn - 1);
            d = min(max(d, 0), Nn - 1);
            bk[j] = d >> 8;
            val[j] = ((unsigned int)s << 8) | (unsigned int)(d & 255);
            atomicAdd(&lcnt[bk[j]], 1);
        }
    }
    __syncthreads();
    if (lcnt[t] > 0) lbase[t] = atomicAdd(&bcnt[t], lcnt[t]);
    __syncthreads();
#pragma unroll
    for (int j = 0; j < 16; ++j) {
        if (ok[j]) {
            int p = lbase[bk[j]] + atomicAdd(&lcur[bk[j]], 1);
            if (p < CAP) buckets[(size_t)bk[j] * CAP + p] = val[j];
        }
    }
}

// ---- shared gemm core (MFMA bf16, alpha fused; optional planar C) ----------
__device__ __forceinline__ void gemm_core(const ushort* __restrict__ A,
                                          const ushort* __restrict__ Bt,
                                          ushort* __restrict__ C,
                                          int M, int K, int Nc,
                                          const void* __restrict__ aS,
                                          const void* __restrict__ aD,
                                          float* __restrict__ alphaS,
                                          float* __restrict__ alphaD,
                                          int H, int f, int gx, int head,
                                          int planar) {
    int tid = threadIdx.x;
    int wave = tid >> 6, lane = tid & 63, quad = lane >> 4, l16 = lane & 15;
    int rbase = gx * 256 + wave * 64;
    int cbase = head * 64;
    floatx4 acc[4][4];
#pragma unroll
    for (int i = 0; i < 4; i++)
#pragma unroll
        for (int j = 0; j < 4; j++) acc[i][j] = (floatx4)0.f;

    for (int kb = 0; kb < K; kb += 32) {
        int k0 = kb + quad * 8;
        short8 a[4], b[4];
#pragma unroll
        for (int mt = 0; mt < 4; mt++) {
            int row = rbase + mt * 16 + l16;
            if (row >= M) row = M - 1;  // clamp; oob rows never stored
            a[mt] = *reinterpret_cast<const short8*>(A + (size_t)row * K + k0);
        }
#pragma unroll
        for (int nt = 0; nt < 4; nt++) {
            int col = cbase + nt * 16 + l16;
            b[nt] = *reinterpret_cast<const short8*>(Bt + (size_t)col * K + k0);
        }
#pragma unroll
        for (int mt = 0; mt < 4; mt++)
#pragma unroll
            for (int nt = 0; nt < 4; nt++)
                acc[mt][nt] = __builtin_amdgcn_mfma_f32_16x16x32_bf16(
                    a[mt], b[nt], acc[mt][nt], 0, 0, 0);
    }
    float asv[4], adv[4];
#pragma unroll
    for (int nt = 0; nt < 4; nt++) {
        int col = cbase + nt * 16 + l16;
        asv[nt] = load_in(aS, col, f);
        adv[nt] = load_in(aD, col, f);
    }
    // C/D layout: col = lane&15, row = quad*4 + reg   [m89-verified]
#pragma unroll
    for (int mt = 0; mt < 4; mt++) {
#pragma unroll
        for (int r = 0; r < 4; r++) {
            int row = rbase + mt * 16 + quad * 4 + r;
            float ps = 0.f, pd = 0.f;
#pragma unroll
            for (int nt = 0; nt < 4; nt++) {
                float w = acc[mt][nt][r];
                ps += w * asv[nt];
                pd += w * adv[nt];
            }
#pragma unroll
            for (int off = 8; off > 0; off >>= 1) {  // reduce over 16 col-lanes
                ps += __shfl_xor(ps, off, 16);
                pd += __shfl_xor(pd, off, 16);
            }
            if (row < M) {
                if (l16 == 0) {
                    alphaS[row * H + head] = ps;
                    alphaD[row * H + head] = pd;
                }
#pragma unroll
                for (int nt = 0; nt < 4; nt++) {
                    int col = cbase + nt * 16 + l16;
                    size_t caddr = planar
                        ? ((size_t)(col >> 7) * M + row) * 128 + (col & 127)
                        : (size_t)row * Nc + col;
                    C[caddr] = f2bf(acc[mt][nt][r]);
                }
            }
        }
    }
}

// ---- fused: gemm1 blocks [0, g1) + CSR pass-2 blocks [g1, g1+NB) -----------
__global__ __launch_bounds__(256) void gemm1_pass2_kernel(
        const ushort* __restrict__ A, const ushort* __restrict__ Bt,
        ushort* __restrict__ C, int M, int K, int Nc,
        const void* __restrict__ aS, const void* __restrict__ aD,
        float* __restrict__ alphaS, float* __restrict__ alphaD,
        const int* __restrict__ flags, int g1, int nbx,
        const int* __restrict__ bcnt, const unsigned int* __restrict__ buckets,
        int* __restrict__ offs, int* __restrict__ csr_src, int Nn) {
    __shared__ int part[256], sc[256], cur[256];
    int bid = blockIdx.x;
    int t = threadIdx.x;
    if (bid < g1) {
        gemm_core(A, Bt, C, M, K, Nc, aS, aD, alphaS, alphaD, 4, flags[0],
                  bid % nbx, bid / nbx, 1);
        return;
    }
    // ---- CSR pass 2: one block per 256-node bucket ----
    int b = bid - g1;
    part[t] = bcnt[t];
    __syncthreads();
#pragma unroll
    for (int off = 1; off < 256; off <<= 1) {   // inclusive scan of bucket sizes
        int v = (t >= off) ? part[t - off] : 0;
        __syncthreads();
        part[t] += v;
        __syncthreads();
    }
    int basepos = (b == 0) ? 0 : part[b - 1];
    int nEdges = min(bcnt[b], CAP);
    sc[t] = 0;
    __syncthreads();
    const unsigned int* bk = buckets + (size_t)b * CAP;
    for (int i = t; i < nEdges; i += 256)
        atomicAdd(&sc[bk[i] & 255], 1);
    __syncthreads();
    int mycount = sc[t];
    __syncthreads();
#pragma unroll
    for (int off = 1; off < 256; off <<= 1) {   // inclusive scan of node counts
        int v = (t >= off) ? sc[t - off] : 0;
        __syncthreads();
        sc[t] += v;
        __syncthreads();
    }
    int excl = sc[t] - mycount;
    int gnode = b * 256 + t;
    if (gnode <= Nn) offs[gnode] = basepos + excl;
    cur[t] = excl;
    __syncthreads();
    for (int i = t; i < nEdges; i += 256) {
        unsigned int v = bk[i];
        int p = atomicAdd(&cur[v & 255], 1);
        csr_src[basepos + p] = (int)(v >> 8);
    }
}

// ---- layer-2 gemm (H=1), standalone ---------------------------------------
__global__ __launch_bounds__(256) void gemm2_kernel(const ushort* __restrict__ A,
                                                    const ushort* __restrict__ Bt,
                                                    ushort* __restrict__ C,
                                                    int M, int K, int Nc,
                                                    const void* __restrict__ aS,
                                                    const void* __restrict__ aD,
                                                    float* __restrict__ alphaS,
                                                    float* __restrict__ alphaD,
                                                    const int* __restrict__ flags) {
    gemm_core(A, Bt, C, M, K, Nc, aS, aD, alphaS, alphaD, 1, flags[0],
              blockIdx.x, blockIdx.y, 0);
}

// ---- wk1: per-edge p (all 4 heads, bf16) + per-node 1/l --------------------
// 1 wave/node; lane = edge slot (64/chunk; avg deg 33 -> mostly one chunk).
// pkA[e] = {src, p0|p1<<16}, pkB[e] = {src, p2|p3<<16}; invl[n][4] = 1/l_h.
__global__ __launch_bounds__(256) void wk1_kernel(const int* __restrict__ csr_src,
                                                  const int* __restrict__ offs,
                                                  const float* __restrict__ asrc,
                                                  const float* __restrict__ adst,
                                                  uint2* __restrict__ pkA,
                                                  uint2* __restrict__ pkB,
                                                  float* __restrict__ invl, int Nn) {
    int wave = threadIdx.x >> 6, lane = threadIdx.x & 63;
    int n = blockIdx.x * 4 + wave;
    if (n >= Nn) return;
    float4 ad = *(const float4*)(adst + (size_t)n * 4);
    int beg = offs[n], end = offs[n + 1];
    float l0 = 0.f, l1 = 0.f, l2 = 0.f, l3 = 0.f;
    for (int e0 = beg; e0 < end; e0 += 64) {
        int e = e0 + lane;
        bool v = e < end;
        int src = v ? csr_src[e] : 0;
        float4 as = *(const float4*)(asrc + (size_t)src * 4);
        float s0 = as.x + ad.x, s1 = as.y + ad.y, s2 = as.z + ad.z, s3 = as.w + ad.w;
        s0 = fmaxf(s0, 0.2f * s0); s1 = fmaxf(s1, 0.2f * s1);
        s2 = fmaxf(s2, 0.2f * s2); s3 = fmaxf(s3, 0.2f * s3);
        float p0 = v ? __expf(s0) : 0.f, p1 = v ? __expf(s1) : 0.f;
        float p2 = v ? __expf(s2) : 0.f, p3 = v ? __expf(s3) : 0.f;
        l0 += p0; l1 += p1; l2 += p2; l3 += p3;
        if (v) {
            uint2 a, b;
            a.x = (unsigned int)src;
            a.y = (unsigned int)f2bf(p0) | ((unsigned int)f2bf(p1) << 16);
            b.x = (unsigned int)src;
            b.y = (unsigned int)f2bf(p2) | ((unsigned int)f2bf(p3) << 16);
            pkA[e] = a; pkB[e] = b;
        }
    }
#pragma unroll
    for (int off = 1; off < 64; off <<= 1) {
        l0 += __shfl_xor(l0, off); l1 += __shfl_xor(l1, off);
        l2 += __shfl_xor(l2, off); l3 += __shfl_xor(l3, off);
    }
    if (lane == 0) {
        float4 iv;
        iv.x = 1.f / (l0 + 1e-16f); iv.y = 1.f / (l1 + 1e-16f);
        iv.z = 1.f / (l2 + 1e-16f); iv.w = 1.f / (l3 + 1e-16f);
        *(float4*)(invl + (size_t)n * 4) = iv;
    }
}

// ---- wk2: layer-2 p (1 head) packed {src16|p_bf16} + 1/l -------------------
__global__ __launch_bounds__(256) void wk2_kernel(const int* __restrict__ csr_src,
                                                  const int* __restrict__ offs,
                                                  const float* __restrict__ asrc,
                                                  const float* __restrict__ adst,
                                                  unsigned int* __restrict__ pk2,
                                                  float* __restrict__ invl2, int Nn) {
    int wave = threadIdx.x >> 6, lane = threadIdx.x & 63;
    int n = blockIdx.x * 4 + wave;
    if (n >= Nn) return;
    float ad = adst[n];
    int beg = offs[n], end = offs[n + 1];
    float l = 0.f;
    for (int e0 = beg; e0 < end; e0 += 64) {
        int e = e0 + lane;
        bool v = e < end;
        int src = v ? csr_src[e] : 0;
        float s = asrc[src] + ad;
        s = fmaxf(s, 0.2f * s);
        float p = v ? __expf(s) : 0.f;
        l += p;
        if (v) pk2[e] = (unsigned int)src | ((unsigned int)f2bf(p) << 16);
    }
#pragma unroll
    for (int off = 1; off < 64; off <<= 1) l += __shfl_xor(l, off);
    if (lane == 0) invl2[n] = 1.f / (l + 1e-16f);
}

// ---- layer-1 aggregation, one 128-ch plane per dispatch --------------------
// 1 wave/node, 4 edges/wave: group g=lane>>4, 8 ch/lane (uint4 gather).
// p from packed stream (lo/hi bf16 by channel half); normalize via invl.
__global__ __launch_bounds__(256) void gat_node1_pass(
        const uint2* __restrict__ pk, const int* __restrict__ offs,
        const float* __restrict__ invl, const ushort* __restrict__ h1p,
        const void* __restrict__ b1, ushort* __restrict__ hmidb,
        int Nn, const int* __restrict__ flags, int plane) {
    int f = flags[0];
    int wave = threadIdx.x >> 6, lane = threadIdx.x & 63;
    int n = blockIdx.x * 4 + wave;
    if (n >= Nn) return;
    int g = lane >> 4, l4 = lane & 15;
    bool hi = l4 >= 8;
    const ushort* base = h1p + (size_t)plane * Nn * 128 + (size_t)l4 * 8;
    int beg = offs[n], end = offs[n + 1];
    float a0 = 0.f, a1 = 0.f, a2 = 0.f, a3 = 0.f;
    float a4 = 0.f, a5 = 0.f, a6 = 0.f, a7 = 0.f;

    int e = beg;
    while (e + 8 <= end) {
        uint2 k0 = pk[e + g];
        uint2 k1 = pk[e + 4 + g];
        uint4 v0 = *(const uint4*)(base + (size_t)k0.x * 128);
        uint4 v1 = *(const uint4*)(base + (size_t)k1.x * 128);
        float p0 = bits2f(hi ? (k0.y & 0xffff0000u) : (k0.y << 16));
        float p1 = bits2f(hi ? (k1.y & 0xffff0000u) : (k1.y << 16));
        a0 += p0 * bits2f(v0.x << 16); a1 += p0 * bits2f(v0.x & 0xffff0000u);
        a2 += p0 * bits2f(v0.y << 16); a3 += p0 * bits2f(v0.y & 0xffff0000u);
        a4 += p0 * bits2f(v0.z << 16); a5 += p0 * bits2f(v0.z & 0xffff0000u);
        a6 += p0 * bits2f(v0.w << 16); a7 += p0 * bits2f(v0.w & 0xffff0000u);
        a0 += p1 * bits2f(v1.x << 16); a1 += p1 * bits2f(v1.x & 0xffff0000u);
        a2 += p1 * bits2f(v1.y << 16); a3 += p1 * bits2f(v1.y & 0xffff0000u);
        a4 += p1 * bits2f(v1.z << 16); a5 += p1 * bits2f(v1.z & 0xffff0000u);
        a6 += p1 * bits2f(v1.w << 16); a7 += p1 * bits2f(v1.w & 0xffff0000u);
        e += 8;
    }
    if (e < end) {                      // masked chunk (<8 edges)
        int i0 = e + g, i1 = e + 4 + g;
        uint2 k0, k1;
        k0.x = 0u; k0.y = 0u; k1.x = 0u; k1.y = 0u;
        if (i0 < end) k0 = pk[i0];
        if (i1 < end) k1 = pk[i1];
        uint4 v0 = *(const uint4*)(base + (size_t)k0.x * 128);
        uint4 v1 = *(const uint4*)(base + (size_t)k1.x * 128);
        float p0 = bits2f(hi ? (k0.y & 0xffff0000u) : (k0.y << 16));
        float p1 = bits2f(hi ? (k1.y & 0xffff0000u) : (k1.y << 16));
        a0 += p0 * bits2f(v0.x << 16); a1 += p0 * bits2f(v0.x & 0xffff0000u);
        a2 += p0 * bits2f(v0.y << 16); a3 += p0 * bits2f(v0.y & 0xffff0000u);
        a4 += p0 * bits2f(v0.z << 16); a5 += p0 * bits2f(v0.z & 0xffff0000u);
        a6 += p0 * bits2f(v0.w << 16); a7 += p0 * bits2f(v0.w & 0xffff0000u);
        a0 += p1 * bits2f(v1.x << 16); a1 += p1 * bits2f(v1.x & 0xffff0000u);
        a2 += p1 * bits2f(v1.y << 16); a3 += p1 * bits2f(v1.y & 0xffff0000u);
        a4 += p1 * bits2f(v1.z << 16); a5 += p1 * bits2f(v1.z & 0xffff0000u);
        a6 += p1 * bits2f(v1.w << 16); a7 += p1 * bits2f(v1.w & 0xffff0000u);
    }
#pragma unroll
    for (int off = 16; off <= 32; off <<= 1) {
        a0 += __shfl_xor(a0, off); a1 += __shfl_xor(a1, off);
        a2 += __shfl_xor(a2, off); a3 += __shfl_xor(a3, off);
        a4 += __shfl_xor(a4, off); a5 += __shfl_xor(a5, off);
        a6 += __shfl_xor(a6, off); a7 += __shfl_xor(a7, off);
    }
    if (lane < 16) {
        int head = plane * 2 + (l4 >> 3);
        float inv = invl[(size_t)n * 4 + head];
        int cb = plane * 128 + l4 * 8;
        float o0 = a0 * inv + load_in(b1, cb + 0, f);
        float o1 = a1 * inv + load_in(b1, cb + 1, f);
        float o2 = a2 * inv + load_in(b1, cb + 2, f);
        float o3 = a3 * inv + load_in(b1, cb + 3, f);
        float o4 = a4 * inv + load_in(b1, cb + 4, f);
        float o5 = a5 * inv + load_in(b1, cb + 5, f);
        float o6 = a6 * inv + load_in(b1, cb + 6, f);
        float o7 = a7 * inv + load_in(b1, cb + 7, f);
        o0 = o0 > 0.f ? o0 : __expf(o0) - 1.f;   // ELU
        o1 = o1 > 0.f ? o1 : __expf(o1) - 1.f;
        o2 = o2 > 0.f ? o2 : __expf(o2) - 1.f;
        o3 = o3 > 0.f ? o3 : __expf(o3) - 1.f;
        o4 = o4 > 0.f ? o4 : __expf(o4) - 1.f;
        o5 = o5 > 0.f ? o5 : __expf(o5) - 1.f;
        o6 = o6 > 0.f ? o6 : __expf(o6) - 1.f;
        o7 = o7 > 0.f ? o7 : __expf(o7) - 1.f;
        uint4 st;
        st.x = (unsigned int)f2bf(o0) | ((unsigned int)f2bf(o1) << 16);
        st.y = (unsigned int)f2bf(o2) | ((unsigned int)f2bf(o3) << 16);
        st.z = (unsigned int)f2bf(o4) | ((unsigned int)f2bf(o5) << 16);
        st.w = (unsigned int)f2bf(o6) | ((unsigned int)f2bf(o7) << 16);
        *(uint4*)(hmidb + (size_t)n * 256 + cb) = st;
    }
}

// ---- layer-2 aggregation: 4 edges/wave, 4ch/lane, packed p -----------------
__global__ __launch_bounds__(256) void gat_node2(const unsigned int* __restrict__ pk2,
                                                 const int* __restrict__ offs,
                                                 const float* __restrict__ invl2,
                                                 const ushort* __restrict__ h2b,
                                                 const void* __restrict__ b2,
                                                 void* __restrict__ out, int Nn,
                                                 const int* __restrict__ flags) {
    int f = flags[0];
    int wave = threadIdx.x >> 6, lane = threadIdx.x & 63;
    int n = blockIdx.x * 4 + wave;
    if (n >= Nn) return;
    int g = lane >> 4, l4 = lane & 15;
    const ushort* base = h2b + (size_t)l4 * 4;
    int beg = offs[n], end = offs[n + 1];
    float a0 = 0.f, a1 = 0.f, a2 = 0.f, a3 = 0.f;

    int e = beg;
    while (e + 8 <= end) {
        unsigned int k0 = pk2[e + g];
        unsigned int k1 = pk2[e + 4 + g];
        uint2 v0 = *(const uint2*)(base + (size_t)(k0 & 0xffffu) * 64);
        uint2 v1 = *(const uint2*)(base + (size_t)(k1 & 0xffffu) * 64);
        float p0 = bits2f(k0 & 0xffff0000u);
        float p1 = bits2f(k1 & 0xffff0000u);
        a0 += p0 * bits2f(v0.x << 16); a1 += p0 * bits2f(v0.x & 0xffff0000u);
        a2 += p0 * bits2f(v0.y << 16); a3 += p0 * bits2f(v0.y & 0xffff0000u);
        a0 += p1 * bits2f(v1.x << 16); a1 += p1 * bits2f(v1.x & 0xffff0000u);
        a2 += p1 * bits2f(v1.y << 16); a3 += p1 * bits2f(v1.y & 0xffff0000u);
        e += 8;
    }
    if (e < end) {
        int i0 = e + g, i1 = e + 4 + g;
        unsigned int k0 = (i0 < end) ? pk2[i0] : 0u;
        unsigned int k1 = (i1 < end) ? pk2[i1] : 0u;
        uint2 v0 = *(const uint2*)(base + (size_t)(k0 & 0xffffu) * 64);
        uint2 v1 = *(const uint2*)(base + (size_t)(k1 & 0xffffu) * 64);
        float p0 = bits2f(k0 & 0xffff0000u);
        float p1 = bits2f(k1 & 0xffff0000u);
        a0 += p0 * bits2f(v0.x << 16); a1 += p0 * bits2f(v0.x & 0xffff0000u);
        a2 += p0 * bits2f(v0.y << 16); a3 += p0 * bits2f(v0.y & 0xffff0000u);
        a0 += p1 * bits2f(v1.x << 16); a1 += p1 * bits2f(v1.x & 0xffff0000u);
        a2 += p1 * bits2f(v1.y << 16); a3 += p1 * bits2f(v1.y & 0xffff0000u);
    }
#pragma unroll
    for (int off = 16; off <= 32; off <<= 1) {
        a0 += __shfl_xor(a0, off); a1 += __shfl_xor(a1, off);
        a2 += __shfl_xor(a2, off); a3 += __shfl_xor(a3, off);
    }
    if (lane < 16) {
        float inv = invl2[n];
        float o0 = a0 * inv + load_in(b2, l4 * 4 + 0, f);
        float o1 = a1 * inv + load_in(b2, l4 * 4 + 1, f);
        float o2 = a2 * inv + load_in(b2, l4 * 4 + 2, f);
        float o3 = a3 * inv + load_in(b2, l4 * 4 + 3, f);
        if (f) {
            float4 st; st.x = o0; st.y = o1; st.z = o2; st.w = o3;
            *(float4*)((float*)out + (size_t)n * 64 + l4 * 4) = st;
        } else {
            uint2 st;
            st.x = (unsigned int)f2bf(o0) | ((unsigned int)f2bf(o1) << 16);
            st.y = (unsigned int)f2bf(o2) | ((unsigned int)f2bf(o3) << 16);
            *(uint2*)((ushort*)out + (size_t)n * 64 + l4 * 4) = st;
        }
    }
}

extern "C" void kernel_launch(void* const* d_in, const int* in_sizes, int n_in,
                              void* d_out, int out_size, void* d_ws, size_t ws_size,
                              hipStream_t stream) {
    const void* x   = d_in[0];
    const void* ei  = d_in[1];
    const void* W1  = d_in[2];
    const void* as1 = d_in[3];
    const void* ad1 = d_in[4];
    const void* b1  = d_in[5];
    const void* W2  = d_in[6];
    const void* as2 = d_in[7];
    const void* ad2 = d_in[8];
    const void* b2  = d_in[9];

    const int Nn = in_sizes[0] / FIN;      // 50000
    const int E  = in_sizes[1] / 2;        // 1600000
    const int ET = E + Nn;
    const int NB = (Nn + 255) >> 8;        // 196 buckets

    char* ws = (char*)d_ws;
    size_t off = 0;
    auto alloc = [&](size_t bytes) {
        size_t o = off;
        off += (bytes + 255) & ~(size_t)255;
        return o;
    };
    ushort* xb    = (ushort*)(ws + alloc((size_t)Nn * FIN * 2));
    ushort* h1b   = (ushort*)(ws + alloc((size_t)Nn * FIN * 2));   // planar [2][Nn][128]
    ushort* hmidb = (ushort*)(ws + alloc((size_t)Nn * FIN * 2));
    ushort* h2b   = (ushort*)(ws + alloc((size_t)Nn * CH * 2));
    ushort* Wt1   = (ushort*)(ws + alloc((size_t)FIN * FIN * 2));
    ushort* Wt2   = (ushort*)(ws + alloc((size_t)CH * FIN * 2));
    float* as1f   = (float*)(ws + alloc((size_t)Nn * H1 * 4));
    float* ad1f   = (float*)(ws + alloc((size_t)Nn * H1 * 4));
    float* as2f   = (float*)(ws + alloc((size_t)Nn * 4));
    float* ad2f   = (float*)(ws + alloc((size_t)Nn * 4));
    float* invl   = (float*)(ws + alloc((size_t)Nn * H1 * 4));
    float* invl2  = (float*)(ws + alloc((size_t)Nn * 4));
    int*   offs   = (int*)(ws + alloc((size_t)(Nn + 1) * 4));
    int*   csr    = (int*)(ws + alloc((size_t)ET * 4));
    uint2* pkA    = (uint2*)(ws + alloc((size_t)ET * 8));
    uint2* pkB    = (uint2*)(ws + alloc((size_t)ET * 8));
    unsigned int* pk2 = (unsigned int*)(ws + alloc((size_t)ET * 4));
    unsigned int* buckets = (unsigned int*)(ws + alloc((size_t)256 * CAP * 4));
    int*   bcnt   = (int*)(ws + alloc(256 * 4));
    int*   flags  = (int*)(ws + alloc(256));
    (void)ws_size; (void)n_in; (void)out_size;

    probe_kernel<<<1, 256, 0, stream>>>((const ushort*)x, (const int*)ei, flags, bcnt);

    // fused prep (convert+transpose) | bucket pass 1
    int PB_conv = (Nn * FIN) / 2048;                       // 8 elem/thread
    int PB_tr   = (FIN * FIN + CH * FIN) / 256;            // 320
    int PB_bkt  = (ET + 4095) / 4096;
    prep_bucket_kernel<<<PB_conv + PB_tr + PB_bkt, 256, 0, stream>>>(
        x, W1, W2, xb, Wt1, Wt2, ei, bcnt, buckets,
        E, ET, Nn, flags, PB_conv, PB_conv + PB_tr);

    // fused: gemm1 (+alpha, planar C) and CSR pass 2
    int nbx = (Nn + 255) / 256;            // 196 row-blocks
    int g1 = nbx * H1;                     // 784 gemm blocks
    gemm1_pass2_kernel<<<g1 + NB, 256, 0, stream>>>(
        xb, Wt1, h1b, Nn, FIN, FIN, as1, ad1, as1f, ad1f,
        flags, g1, nbx, bcnt, buckets, offs, csr, Nn);

    // layer-1 weights, then one dispatch per 128-ch plane (time-separated)
    wk1_kernel<<<(Nn + 3) / 4, 256, 0, stream>>>(csr, offs, as1f, ad1f, pkA, pkB, invl, Nn);
    gat_node1_pass<<<(Nn + 3) / 4, 256, 0, stream>>>(
        pkA, offs, invl, h1b, b1, hmidb, Nn, flags, 0);
    gat_node1_pass<<<(Nn + 3) / 4, 256, 0, stream>>>(
        pkB, offs, invl, h1b, b1, hmidb, Nn, flags, 1);

    // layer 2
    gemm2_kernel<<<dim3((Nn + 255) / 256, 1), 256, 0, stream>>>(
        hmidb, Wt2, h2b, Nn, FIN, CH, as2, ad2, as2f, ad2f, flags);
    wk2_kernel<<<(Nn + 3) / 4, 256, 0, stream>>>(csr, offs, as2f, ad2f, pk2, invl2, Nn);
    gat_node2<<<(Nn + 3) / 4, 256, 0, stream>>>(pk2, offs, invl2, h2b, b2, d_out, Nn, flags);
}

// Round 10
// 373.142 us; speedup vs baseline: 1.0645x; 1.0645x over previous
//
#include <hip/hip_runtime.h>

// ---------------------------------------------------------------------------
// GAT encoder, 2 layers, MI355X — round 10.
// Dtype-adaptive (probe: f32-vs-bf16 floats, i64-vs-i32 indices).
// bf16 internal, f32 accumulation, direct-sum softmax (logits bounded).
// CSR: bucket sort (pass1 fused w/ prep; pass2 fused w/ gemm1).
// r9 lesson: separate wk kernels cost more than they save. r10:
//   pass0 (plane 0) computes all-head p inline (f32), aggregates plane 0,
//     and EMITS packed {src, p2|p3} + invl23 for pass1 as a side effect.
//   pass1 (plane 1) = pure packed consumer, 16 edges/iter (4 gathers in
//     flight; r9 sat at 2.7/3.6 TB/s with MLP 2).
//   node2 = r8-style inline exp (wk2 deleted).
// 7 dispatches: probe, prep+bucket, gemm1+pass2, pass0, pass1, gemm2, node2.
// ---------------------------------------------------------------------------

typedef __attribute__((ext_vector_type(8))) short short8;
typedef __attribute__((ext_vector_type(4))) float floatx4;

#define FIN 256
#define H1 4
#define CH 64
#define CAP 16384   // bucket capacity (avg fill 8.4K, sigma ~92)

__device__ __forceinline__ float bf2f(ushort u) {
    union { unsigned int i; float f; } v; v.i = ((unsigned int)u) << 16; return v.f;
}
__device__ __forceinline__ ushort f2bf(float f) {
    union { float f; unsigned int i; } v; v.f = f;
    unsigned int r = v.i + 0x7fffu + ((v.i >> 16) & 1u);  // RNE
    return (ushort)(r >> 16);
}
__device__ __forceinline__ float bits2f(unsigned int b) {
    union { unsigned int i; float f; } v; v.i = b; return v.f;
}
__device__ __forceinline__ float load_in(const void* p, int i, int f) {
    return f ? ((const float*)p)[i] : bf2f(((const ushort*)p)[i]);
}
__device__ __forceinline__ int load_idx(const void* p, long long i, int f64) {
    return f64 ? (int)((const long long*)p)[i] : ((const int*)p)[i];
}

// ---- dtype probe + bcnt zero ----------------------------------------------
__global__ __launch_bounds__(256) void probe_kernel(const ushort* __restrict__ x,
                                                    const int* __restrict__ ei,
                                                    int* __restrict__ flags,
                                                    int* __restrict__ bcnt) {
    __shared__ int s_nan, s_odd;
    int t = threadIdx.x;
    bcnt[t] = 0;
    if (t == 0) { s_nan = 0; s_odd = 0; }
    __syncthreads();
    int nanc = 0, oddc = 0;
    for (int i = t; i < 16384; i += 256) {
        ushort u = x[i];
        if (((u >> 7) & 0xFF) == 0xFF) nanc++;
    }
    for (int i = t; i < 2048; i += 256)
        if (ei[2 * i + 1] != 0) oddc++;
    if (nanc) atomicAdd(&s_nan, nanc);
    if (oddc) atomicAdd(&s_odd, oddc);
    __syncthreads();
    if (t == 0) {
        flags[0] = (s_nan >= 2) ? 1 : 0;  // 1 = floats are f32
        flags[1] = (s_odd == 0) ? 1 : 0;  // 1 = indices are int64
    }
}

// ---- fused: x convert (8/thr) | W transposes | CSR bucket pass 1 -----------
__global__ __launch_bounds__(256) void prep_bucket_kernel(
        const void* __restrict__ x, const void* __restrict__ W1,
        const void* __restrict__ W2, ushort* __restrict__ xb,
        ushort* __restrict__ Wt1, ushort* __restrict__ Wt2,
        const void* __restrict__ ei, int* __restrict__ bcnt,
        unsigned int* __restrict__ buckets,
        int E, int Etot, int Nn, const int* __restrict__ flags,
        int PB_conv, int PB_tr_end) {
    __shared__ int lcnt[256], lbase[256], lcur[256];
    int bid = blockIdx.x, t = threadIdx.x;
    int f = flags[0];
    if (bid < PB_conv) {                       // ---- x -> bf16, 8 elem/thread
        int i0 = bid * 2048 + t * 8;
        if (f) {
            float4 v0 = ((const float4*)x)[i0 / 4];
            float4 v1 = ((const float4*)x)[i0 / 4 + 1];
            ushort4 o0, o1;
            o0.x = f2bf(v0.x); o0.y = f2bf(v0.y); o0.z = f2bf(v0.z); o0.w = f2bf(v0.w);
            o1.x = f2bf(v1.x); o1.y = f2bf(v1.y); o1.z = f2bf(v1.z); o1.w = f2bf(v1.w);
            *(ushort4*)(xb + i0) = o0;
            *(ushort4*)(xb + i0 + 4) = o1;
        } else {
            *(uint4*)(xb + i0) = ((const uint4*)x)[i0 / 8];
        }
        return;
    }
    if (bid < PB_tr_end) {                     // ---- W1^T, W2^T
        int j = (bid - PB_conv) * 256 + t;
        if (j < FIN * FIN) {
            int n = j / FIN, k = j % FIN;
            Wt1[j] = f2bf(load_in(W1, k * FIN + n, f));
        } else {
            int jj = j - FIN * FIN;
            int n = jj / FIN, k = jj % FIN;
            Wt2[jj] = f2bf(load_in(W2, k * CH + n, f));
        }
        return;
    }
    // ---- CSR pass 1: bucket partition, 16 edges/thread (4096/block)
    lcnt[t] = 0; lcur[t] = 0;
    __syncthreads();
    int f64 = flags[1];
    int base = (bid - PB_tr_end) * 4096 + t;
    unsigned int val[16]; int bk[16]; bool ok[16];
#pragma unroll
    for (int j = 0; j < 16; ++j) {
        int e = base + j * 256;
        ok[j] = e < Etot;
        bk[j] = 0; val[j] = 0;
        if (ok[j]) {
            int s, d;
            if (e < E) {
                s = load_idx(ei, e, f64);
                d = load_idx(ei, (long long)E + e, f64);
            } else {
                s = d = e - E;   // self-loops appended
            }
            s = min(max(s, 0), Nn - 1);
            d = min(max(d, 0), Nn - 1);
            bk[j] = d >> 8;
            val[j] = ((unsigned int)s << 8) | (unsigned int)(d & 255);
            atomicAdd(&lcnt[bk[j]], 1);
        }
    }
    __syncthreads();
    if (lcnt[t] > 0) lbase[t] = atomicAdd(&bcnt[t], lcnt[t]);
    __syncthreads();
#pragma unroll
    for (int j = 0; j < 16; ++j) {
        if (ok[j]) {
            int p = lbase[bk[j]] + atomicAdd(&lcur[bk[j]], 1);
            if (p < CAP) buckets[(size_t)bk[j] * CAP + p] = val[j];
        }
    }
}

// ---- shared gemm core (MFMA bf16, alpha fused; optional planar C) ----------
__device__ __forceinline__ void gemm_core(const ushort* __restrict__ A,
                                          const ushort* __restrict__ Bt,
                                          ushort* __restrict__ C,
                                          int M, int K, int Nc,
                                          const void* __restrict__ aS,
                                          const void* __restrict__ aD,
                                          float* __restrict__ alphaS,
                                          float* __restrict__ alphaD,
                                          int H, int f, int gx, int head,
                                          int planar) {
    int tid = threadIdx.x;
    int wave = tid >> 6, lane = tid & 63, quad = lane >> 4, l16 = lane & 15;
    int rbase = gx * 256 + wave * 64;
    int cbase = head * 64;
    floatx4 acc[4][4];
#pragma unroll
    for (int i = 0; i < 4; i++)
#pragma unroll
        for (int j = 0; j < 4; j++) acc[i][j] = (floatx4)0.f;

    for (int kb = 0; kb < K; kb += 32) {
        int k0 = kb + quad * 8;
        short8 a[4], b[4];
#pragma unroll
        for (int mt = 0; mt < 4; mt++) {
            int row = rbase + mt * 16 + l16;
            if (row >= M) row = M - 1;  // clamp; oob rows never stored
            a[mt] = *reinterpret_cast<const short8*>(A + (size_t)row * K + k0);
        }
#pragma unroll
        for (int nt = 0; nt < 4; nt++) {
            int col = cbase + nt * 16 + l16;
            b[nt] = *reinterpret_cast<const short8*>(Bt + (size_t)col * K + k0);
        }
#pragma unroll
        for (int mt = 0; mt < 4; mt++)
#pragma unroll
            for (int nt = 0; nt < 4; nt++)
                acc[mt][nt] = __builtin_amdgcn_mfma_f32_16x16x32_bf16(
                    a[mt], b[nt], acc[mt][nt], 0, 0, 0);
    }
    float asv[4], adv[4];
#pragma unroll
    for (int nt = 0; nt < 4; nt++) {
        int col = cbase + nt * 16 + l16;
        asv[nt] = load_in(aS, col, f);
        adv[nt] = load_in(aD, col, f);
    }
    // C/D layout: col = lane&15, row = quad*4 + reg   [m89-verified]
#pragma unroll
    for (int mt = 0; mt < 4; mt++) {
#pragma unroll
        for (int r = 0; r < 4; r++) {
            int row = rbase + mt * 16 + quad * 4 + r;
            float ps = 0.f, pd = 0.f;
#pragma unroll
            for (int nt = 0; nt < 4; nt++) {
                float w = acc[mt][nt][r];
                ps += w * asv[nt];
                pd += w * adv[nt];
            }
#pragma unroll
            for (int off = 8; off > 0; off >>= 1) {  // reduce over 16 col-lanes
                ps += __shfl_xor(ps, off, 16);
                pd += __shfl_xor(pd, off, 16);
            }
            if (row < M) {
                if (l16 == 0) {
                    alphaS[row * H + head] = ps;
                    alphaD[row * H + head] = pd;
                }
#pragma unroll
                for (int nt = 0; nt < 4; nt++) {
                    int col = cbase + nt * 16 + l16;
                    size_t caddr = planar
                        ? ((size_t)(col >> 7) * M + row) * 128 + (col & 127)
                        : (size_t)row * Nc + col;
                    C[caddr] = f2bf(acc[mt][nt][r]);
                }
            }
        }
    }
}

// ---- fused: gemm1 blocks [0, g1) + CSR pass-2 blocks [g1, g1+NB) -----------
__global__ __launch_bounds__(256) void gemm1_pass2_kernel(
        const ushort* __restrict__ A, const ushort* __restrict__ Bt,
        ushort* __restrict__ C, int M, int K, int Nc,
        const void* __restrict__ aS, const void* __restrict__ aD,
        float* __restrict__ alphaS, float* __restrict__ alphaD,
        const int* __restrict__ flags, int g1, int nbx,
        const int* __restrict__ bcnt, const unsigned int* __restrict__ buckets,
        int* __restrict__ offs, int* __restrict__ csr_src, int Nn) {
    __shared__ int part[256], sc[256], cur[256];
    int bid = blockIdx.x;
    int t = threadIdx.x;
    if (bid < g1) {
        gemm_core(A, Bt, C, M, K, Nc, aS, aD, alphaS, alphaD, 4, flags[0],
                  bid % nbx, bid / nbx, 1);
        return;
    }
    // ---- CSR pass 2: one block per 256-node bucket ----
    int b = bid - g1;
    part[t] = bcnt[t];
    __syncthreads();
#pragma unroll
    for (int off = 1; off < 256; off <<= 1) {   // inclusive scan of bucket sizes
        int v = (t >= off) ? part[t - off] : 0;
        __syncthreads();
        part[t] += v;
        __syncthreads();
    }
    int basepos = (b == 0) ? 0 : part[b - 1];
    int nEdges = min(bcnt[b], CAP);
    sc[t] = 0;
    __syncthreads();
    const unsigned int* bk = buckets + (size_t)b * CAP;
    for (int i = t; i < nEdges; i += 256)
        atomicAdd(&sc[bk[i] & 255], 1);
    __syncthreads();
    int mycount = sc[t];
    __syncthreads();
#pragma unroll
    for (int off = 1; off < 256; off <<= 1) {   // inclusive scan of node counts
        int v = (t >= off) ? sc[t - off] : 0;
        __syncthreads();
        sc[t] += v;
        __syncthreads();
    }
    int excl = sc[t] - mycount;
    int gnode = b * 256 + t;
    if (gnode <= Nn) offs[gnode] = basepos + excl;
    cur[t] = excl;
    __syncthreads();
    for (int i = t; i < nEdges; i += 256) {
        unsigned int v = bk[i];
        int p = atomicAdd(&cur[v & 255], 1);
        csr_src[basepos + p] = (int)(v >> 8);
    }
}

// ---- layer-2 gemm (H=1), standalone ---------------------------------------
__global__ __launch_bounds__(256) void gemm2_kernel(const ushort* __restrict__ A,
                                                    const ushort* __restrict__ Bt,
                                                    ushort* __restrict__ C,
                                                    int M, int K, int Nc,
                                                    const void* __restrict__ aS,
                                                    const void* __restrict__ aD,
                                                    float* __restrict__ alphaS,
                                                    float* __restrict__ alphaD,
                                                    const int* __restrict__ flags) {
    gemm_core(A, Bt, C, M, K, Nc, aS, aD, alphaS, alphaD, 1, flags[0],
              blockIdx.x, blockIdx.y, 0);
}

// ---- pass 0: plane-0 aggregation + emit packed p for pass 1 ----------------
// 1 wave/node, 4 edges/wave (group g = lane>>4), 8 ch/lane (uint4 gather).
// Computes all 4 heads' p inline (f32): uses h0/h1 for its own accumulation,
// packs {src, p2|p3 bf16} -> pkB and writes invl23 for pass 1.
__global__ __launch_bounds__(256) void gat_node1_p0(
        const int* __restrict__ csr_src, const int* __restrict__ offs,
        const float* __restrict__ asrc, const float* __restrict__ adst,
        const ushort* __restrict__ h1p, const void* __restrict__ b1,
        ushort* __restrict__ hmidb, uint2* __restrict__ pkB,
        float* __restrict__ invl23, int Nn, const int* __restrict__ flags) {
    int f = flags[0];
    int wave = threadIdx.x >> 6, lane = threadIdx.x & 63;
    int n = blockIdx.x * 4 + wave;
    if (n >= Nn) return;
    int g = lane >> 4, l4 = lane & 15;
    bool hi = l4 >= 8;
    float4 ad = *(const float4*)(adst + (size_t)n * 4);
    const ushort* base = h1p + (size_t)l4 * 8;           // plane 0
    int beg = offs[n], end = offs[n + 1];
    float a0 = 0.f, a1 = 0.f, a2 = 0.f, a3 = 0.f;
    float a4 = 0.f, a5 = 0.f, a6 = 0.f, a7 = 0.f;
    float l0 = 0.f, l1 = 0.f, l2 = 0.f, l3 = 0.f;

    int e = beg;
    while (true) {
        bool full = (e + 8 <= end);
        int i0 = e + g, i1 = e + 4 + g;
        bool ok0 = full || (i0 < end), ok1 = full || (i1 < end);
        if (!full && e >= end) break;
        int s0 = csr_src[ok0 ? i0 : beg];
        int s1 = csr_src[ok1 ? i1 : beg];
        float4 A0 = *(const float4*)(asrc + (size_t)s0 * 4);
        float4 A1 = *(const float4*)(asrc + (size_t)s1 * 4);
        uint4 v0 = *(const uint4*)(base + (size_t)s0 * 128);
        uint4 v1 = *(const uint4*)(base + (size_t)s1 * 128);
        // edge 0
        {
            float t0 = A0.x + ad.x, t1 = A0.y + ad.y, t2 = A0.z + ad.z, t3 = A0.w + ad.w;
            t0 = fmaxf(t0, 0.2f * t0); t1 = fmaxf(t1, 0.2f * t1);
            t2 = fmaxf(t2, 0.2f * t2); t3 = fmaxf(t3, 0.2f * t3);
            float p0 = ok0 ? __expf(t0) : 0.f, p1 = ok0 ? __expf(t1) : 0.f;
            float p2 = ok0 ? __expf(t2) : 0.f, p3 = ok0 ? __expf(t3) : 0.f;
            l0 += p0; l1 += p1; l2 += p2; l3 += p3;
            float p = hi ? p1 : p0;
            a0 += p * bits2f(v0.x << 16); a1 += p * bits2f(v0.x & 0xffff0000u);
            a2 += p * bits2f(v0.y << 16); a3 += p * bits2f(v0.y & 0xffff0000u);
            a4 += p * bits2f(v0.z << 16); a5 += p * bits2f(v0.z & 0xffff0000u);
            a6 += p * bits2f(v0.w << 16); a7 += p * bits2f(v0.w & 0xffff0000u);
            if (l4 == 0 && ok0) {
                uint2 pk;
                pk.x = (unsigned int)s0;
                pk.y = (unsigned int)f2bf(p2) | ((unsigned int)f2bf(p3) << 16);
                pkB[i0] = pk;
            }
        }
        // edge 1
        {
            float t0 = A1.x + ad.x, t1 = A1.y + ad.y, t2 = A1.z + ad.z, t3 = A1.w + ad.w;
            t0 = fmaxf(t0, 0.2f * t0); t1 = fmaxf(t1, 0.2f * t1);
            t2 = fmaxf(t2, 0.2f * t2); t3 = fmaxf(t3, 0.2f * t3);
            float p0 = ok1 ? __expf(t0) : 0.f, p1 = ok1 ? __expf(t1) : 0.f;
            float p2 = ok1 ? __expf(t2) : 0.f, p3 = ok1 ? __expf(t3) : 0.f;
            l0 += p0; l1 += p1; l2 += p2; l3 += p3;
            float p = hi ? p1 : p0;
            a0 += p * bits2f(v1.x << 16); a1 += p * bits2f(v1.x & 0xffff0000u);
            a2 += p * bits2f(v1.y << 16); a3 += p * bits2f(v1.y & 0xffff0000u);
            a4 += p * bits2f(v1.z << 16); a5 += p * bits2f(v1.z & 0xffff0000u);
            a6 += p * bits2f(v1.w << 16); a7 += p * bits2f(v1.w & 0xffff0000u);
            if (l4 == 0 && ok1) {
                uint2 pk;
                pk.x = (unsigned int)s1;
                pk.y = (unsigned int)f2bf(p2) | ((unsigned int)f2bf(p3) << 16);
                pkB[i1] = pk;
            }
        }
        e += 8;
        if (!full) break;
    }
    // reduce across the 4 edge-groups only (xor 16, 32)
#pragma unroll
    for (int off = 16; off <= 32; off <<= 1) {
        a0 += __shfl_xor(a0, off); a1 += __shfl_xor(a1, off);
        a2 += __shfl_xor(a2, off); a3 += __shfl_xor(a3, off);
        a4 += __shfl_xor(a4, off); a5 += __shfl_xor(a5, off);
        a6 += __shfl_xor(a6, off); a7 += __shfl_xor(a7, off);
        l0 += __shfl_xor(l0, off); l1 += __shfl_xor(l1, off);
        l2 += __shfl_xor(l2, off); l3 += __shfl_xor(l3, off);
    }
    if (lane < 16) {
        float inv = 1.f / ((hi ? l1 : l0) + 1e-16f);
        int cb = l4 * 8;                                  // plane-0 channels
        float o0 = a0 * inv + load_in(b1, cb + 0, f);
        float o1 = a1 * inv + load_in(b1, cb + 1, f);
        float o2 = a2 * inv + load_in(b1, cb + 2, f);
        float o3 = a3 * inv + load_in(b1, cb + 3, f);
        float o4 = a4 * inv + load_in(b1, cb + 4, f);
        float o5 = a5 * inv + load_in(b1, cb + 5, f);
        float o6 = a6 * inv + load_in(b1, cb + 6, f);
        float o7 = a7 * inv + load_in(b1, cb + 7, f);
        o0 = o0 > 0.f ? o0 : __expf(o0) - 1.f;            // ELU
        o1 = o1 > 0.f ? o1 : __expf(o1) - 1.f;
        o2 = o2 > 0.f ? o2 : __expf(o2) - 1.f;
        o3 = o3 > 0.f ? o3 : __expf(o3) - 1.f;
        o4 = o4 > 0.f ? o4 : __expf(o4) - 1.f;
        o5 = o5 > 0.f ? o5 : __expf(o5) - 1.f;
        o6 = o6 > 0.f ? o6 : __expf(o6) - 1.f;
        o7 = o7 > 0.f ? o7 : __expf(o7) - 1.f;
        uint4 st;
        st.x = (unsigned int)f2bf(o0) | ((unsigned int)f2bf(o1) << 16);
        st.y = (unsigned int)f2bf(o2) | ((unsigned int)f2bf(o3) << 16);
        st.z = (unsigned int)f2bf(o4) | ((unsigned int)f2bf(o5) << 16);
        st.w = (unsigned int)f2bf(o6) | ((unsigned int)f2bf(o7) << 16);
        *(uint4*)(hmidb + (size_t)n * 256 + cb) = st;
        if (l4 == 0) {
            float2 iv;
            iv.x = 1.f / (l2 + 1e-16f);
            iv.y = 1.f / (l3 + 1e-16f);
            *(float2*)(invl23 + (size_t)n * 2) = iv;
        }
    }
}

// ---- pass 1: plane-1 aggregation, packed-p consumer, 16 edges/iter ---------
__global__ __launch_bounds__(256) void gat_node1_p1(
        const uint2* __restrict__ pk, const int* __restrict__ offs,
        const float* __restrict__ invl23, const ushort* __restrict__ h1p,
        const void* __restrict__ b1, ushort* __restrict__ hmidb,
        int Nn, const int* __restrict__ flags) {
    int f = flags[0];
    int wave = threadIdx.x >> 6, lane = threadIdx.x & 63;
    int n = blockIdx.x * 4 + wave;
    if (n >= Nn) return;
    int g = lane >> 4, l4 = lane & 15;
    bool hi = l4 >= 8;
    const ushort* base = h1p + (size_t)Nn * 128 + (size_t)l4 * 8;   // plane 1
    int beg = offs[n], end = offs[n + 1];
    float a0 = 0.f, a1 = 0.f, a2 = 0.f, a3 = 0.f;
    float a4 = 0.f, a5 = 0.f, a6 = 0.f, a7 = 0.f;

    int e = beg;
    while (e + 16 <= end) {
        uint2 k0 = pk[e + g],      k1 = pk[e + 4 + g];
        uint2 k2 = pk[e + 8 + g],  k3 = pk[e + 12 + g];
        uint4 v0 = *(const uint4*)(base + (size_t)k0.x * 128);
        uint4 v1 = *(const uint4*)(base + (size_t)k1.x * 128);
        uint4 v2 = *(const uint4*)(base + (size_t)k2.x * 128);
        uint4 v3 = *(const uint4*)(base + (size_t)k3.x * 128);
        float p0 = bits2f(hi ? (k0.y & 0xffff0000u) : (k0.y << 16));
        float p1 = bits2f(hi ? (k1.y & 0xffff0000u) : (k1.y << 16));
        float p2 = bits2f(hi ? (k2.y & 0xffff0000u) : (k2.y << 16));
        float p3 = bits2f(hi ? (k3.y & 0xffff0000u) : (k3.y << 16));
        a0 += p0 * bits2f(v0.x << 16); a1 += p0 * bits2f(v0.x & 0xffff0000u);
        a2 += p0 * bits2f(v0.y << 16); a3 += p0 * bits2f(v0.y & 0xffff0000u);
        a4 += p0 * bits2f(v0.z << 16); a5 += p0 * bits2f(v0.z & 0xffff0000u);
        a6 += p0 * bits2f(v0.w << 16); a7 += p0 * bits2f(v0.w & 0xffff0000u);
        a0 += p1 * bits2f(v1.x << 16); a1 += p1 * bits2f(v1.x & 0xffff0000u);
        a2 += p1 * bits2f(v1.y << 16); a3 += p1 * bits2f(v1.y & 0xffff0000u);
        a4 += p1 * bits2f(v1.z << 16); a5 += p1 * bits2f(v1.z & 0xffff0000u);
        a6 += p1 * bits2f(v1.w << 16); a7 += p1 * bits2f(v1.w & 0xffff0000u);
        a0 += p2 * bits2f(v2.x << 16); a1 += p2 * bits2f(v2.x & 0xffff0000u);
        a2 += p2 * bits2f(v2.y << 16); a3 += p2 * bits2f(v2.y & 0xffff0000u);
        a4 += p2 * bits2f(v2.z << 16); a5 += p2 * bits2f(v2.z & 0xffff0000u);
        a6 += p2 * bits2f(v2.w << 16); a7 += p2 * bits2f(v2.w & 0xffff0000u);
        a0 += p3 * bits2f(v3.x << 16); a1 += p3 * bits2f(v3.x & 0xffff0000u);
        a2 += p3 * bits2f(v3.y << 16); a3 += p3 * bits2f(v3.y & 0xffff0000u);
        a4 += p3 * bits2f(v3.z << 16); a5 += p3 * bits2f(v3.z & 0xffff0000u);
        a6 += p3 * bits2f(v3.w << 16); a7 += p3 * bits2f(v3.w & 0xffff0000u);
        e += 16;
    }
    if (e < end) {                      // masked chunk (<16 edges)
        uint2 kk[4];
#pragma unroll
        for (int j = 0; j < 4; ++j) {
            int i = e + 4 * j + g;
            kk[j].x = 0u; kk[j].y = 0u;
            if (i < end) kk[j] = pk[i];
        }
#pragma unroll
        for (int j = 0; j < 4; ++j) {
            uint4 v = *(const uint4*)(base + (size_t)kk[j].x * 128);
            float p = bits2f(hi ? (kk[j].y & 0xffff0000u) : (kk[j].y << 16));
            a0 += p * bits2f(v.x << 16); a1 += p * bits2f(v.x & 0xffff0000u);
            a2 += p * bits2f(v.y << 16); a3 += p * bits2f(v.y & 0xffff0000u);
            a4 += p * bits2f(v.z << 16); a5 += p * bits2f(v.z & 0xffff0000u);
            a6 += p * bits2f(v.w << 16); a7 += p * bits2f(v.w & 0xffff0000u);
        }
    }
#pragma unroll
    for (int off = 16; off <= 32; off <<= 1) {
        a0 += __shfl_xor(a0, off); a1 += __shfl_xor(a1, off);
        a2 += __shfl_xor(a2, off); a3 += __shfl_xor(a3, off);
        a4 += __shfl_xor(a4, off); a5 += __shfl_xor(a5, off);
        a6 += __shfl_xor(a6, off); a7 += __shfl_xor(a7, off);
    }
    if (lane < 16) {
        float inv = invl23[(size_t)n * 2 + (hi ? 1 : 0)];
        int cb = 128 + l4 * 8;                            // plane-1 channels
        float o0 = a0 * inv + load_in(b1, cb + 0, f);
        float o1 = a1 * inv + load_in(b1, cb + 1, f);
        float o2 = a2 * inv + load_in(b1, cb + 2, f);
        float o3 = a3 * inv + load_in(b1, cb + 3, f);
        float o4 = a4 * inv + load_in(b1, cb + 4, f);
        float o5 = a5 * inv + load_in(b1, cb + 5, f);
        float o6 = a6 * inv + load_in(b1, cb + 6, f);
        float o7 = a7 * inv + load_in(b1, cb + 7, f);
        o0 = o0 > 0.f ? o0 : __expf(o0) - 1.f;            // ELU
        o1 = o1 > 0.f ? o1 : __expf(o1) - 1.f;
        o2 = o2 > 0.f ? o2 : __expf(o2) - 1.f;
        o3 = o3 > 0.f ? o3 : __expf(o3) - 1.f;
        o4 = o4 > 0.f ? o4 : __expf(o4) - 1.f;
        o5 = o5 > 0.f ? o5 : __expf(o5) - 1.f;
        o6 = o6 > 0.f ? o6 : __expf(o6) - 1.f;
        o7 = o7 > 0.f ? o7 : __expf(o7) - 1.f;
        uint4 st;
        st.x = (unsigned int)f2bf(o0) | ((unsigned int)f2bf(o1) << 16);
        st.y = (unsigned int)f2bf(o2) | ((unsigned int)f2bf(o3) << 16);
        st.z = (unsigned int)f2bf(o4) | ((unsigned int)f2bf(o5) << 16);
        st.w = (unsigned int)f2bf(o6) | ((unsigned int)f2bf(o7) << 16);
        *(uint4*)(hmidb + (size_t)n * 256 + cb) = st;
    }
}

// ---- layer-2 aggregation: 1 wave/node, 4 edges/wave, inline exp ------------
__global__ __launch_bounds__(256) void gat_node2(const int* __restrict__ csr_src,
                                                 const int* __restrict__ offs,
                                                 const float* __restrict__ asrc,
                                                 const float* __restrict__ adst,
                                                 const ushort* __restrict__ h2b,
                                                 const void* __restrict__ b2,
                                                 void* __restrict__ out, int Nn,
                                                 const int* __restrict__ flags) {
    int f = flags[0];
    int wave = threadIdx.x >> 6, lane = threadIdx.x & 63;
    int n = blockIdx.x * 4 + wave;
    if (n >= Nn) return;
    int q = lane >> 4, l4 = lane & 15;
    float ad = adst[n];
    int beg = offs[n], end = offs[n + 1];
    float a0 = 0.f, a1 = 0.f, a2 = 0.f, a3 = 0.f, l = 0.f;

    int e = beg;
    while (e + 16 <= end) {
        int sj[4]; float aj[4]; uint2 vj[4];
#pragma unroll
        for (int j = 0; j < 4; ++j) sj[j] = csr_src[e + 4 * j + q];
#pragma unroll
        for (int j = 0; j < 4; ++j) {
            aj[j] = asrc[sj[j]];
            vj[j] = *(const uint2*)(h2b + (size_t)sj[j] * 64 + (size_t)l4 * 4);
        }
#pragma unroll
        for (int j = 0; j < 4; ++j) {
            float s = aj[j] + ad;
            s = fmaxf(s, 0.2f * s);
            float p = __expf(s);
            l += p;
            a0 += p * bits2f(vj[j].x << 16); a1 += p * bits2f(vj[j].x & 0xffff0000u);
            a2 += p * bits2f(vj[j].y << 16); a3 += p * bits2f(vj[j].y & 0xffff0000u);
        }
        e += 16;
    }
    if (e < end) {                    // masked tail (<16 edges)
        int sj[4]; float aj[4]; uint2 vj[4];
#pragma unroll
        for (int j = 0; j < 4; ++j) {
            int ei = e + 4 * j + q;
            sj[j] = csr_src[ei < end ? ei : beg];
        }
#pragma unroll
        for (int j = 0; j < 4; ++j) {
            int ei = e + 4 * j + q;
            aj[j] = (ei < end) ? asrc[sj[j]] : -1e30f;
            vj[j] = *(const uint2*)(h2b + (size_t)sj[j] * 64 + (size_t)l4 * 4);
        }
#pragma unroll
        for (int j = 0; j < 4; ++j) {
            float s = aj[j] + ad;
            s = fmaxf(s, 0.2f * s);
            float p = __expf(s);
            l += p;
            a0 += p * bits2f(vj[j].x << 16); a1 += p * bits2f(vj[j].x & 0xffff0000u);
            a2 += p * bits2f(vj[j].y << 16); a3 += p * bits2f(vj[j].y & 0xffff0000u);
        }
    }
#pragma unroll
    for (int off = 16; off <= 32; off <<= 1) {
        a0 += __shfl_xor(a0, off); a1 += __shfl_xor(a1, off);
        a2 += __shfl_xor(a2, off); a3 += __shfl_xor(a3, off);
        l  += __shfl_xor(l, off);
    }
    if (lane < 16) {
        float inv = 1.f / (l + 1e-16f);
        float o0 = a0 * inv + load_in(b2, l4 * 4 + 0, f);
        float o1 = a1 * inv + load_in(b2, l4 * 4 + 1, f);
        float o2 = a2 * inv + load_in(b2, l4 * 4 + 2, f);
        float o3 = a3 * inv + load_in(b2, l4 * 4 + 3, f);
        if (f) {
            float4 st; st.x = o0; st.y = o1; st.z = o2; st.w = o3;
            *(float4*)((float*)out + (size_t)n * 64 + l4 * 4) = st;
        } else {
            uint2 st;
            st.x = (unsigned int)f2bf(o0) | ((unsigned int)f2bf(o1) << 16);
            st.y = (unsigned int)f2bf(o2) | ((unsigned int)f2bf(o3) << 16);
            *(uint2*)((ushort*)out + (size_t)n * 64 + l4 * 4) = st;
        }
    }
}

extern "C" void kernel_launch(void* const* d_in, const int* in_sizes, int n_in,
                              void* d_out, int out_size, void* d_ws, size_t ws_size,
                              hipStream_t stream) {
    const void* x   = d_in[0];
    const void* ei  = d_in[1];
    const void* W1  = d_in[2];
    const void* as1 = d_in[3];
    const void* ad1 = d_in[4];
    const void* b1  = d_in[5];
    const void* W2  = d_in[6];
    const void* as2 = d_in[7];
    const void* ad2 = d_in[8];
    const void* b2  = d_in[9];

    const int Nn = in_sizes[0] / FIN;      // 50000
    const int E  = in_sizes[1] / 2;        // 1600000
    const int ET = E + Nn;
    const int NB = (Nn + 255) >> 8;        // 196 buckets

    char* ws = (char*)d_ws;
    size_t off = 0;
    auto alloc = [&](size_t bytes) {
        size_t o = off;
        off += (bytes + 255) & ~(size_t)255;
        return o;
    };
    ushort* xb    = (ushort*)(ws + alloc((size_t)Nn * FIN * 2));
    ushort* h1b   = (ushort*)(ws + alloc((size_t)Nn * FIN * 2));   // planar [2][Nn][128]
    ushort* hmidb = (ushort*)(ws + alloc((size_t)Nn * FIN * 2));
    ushort* h2b   = (ushort*)(ws + alloc((size_t)Nn * CH * 2));
    ushort* Wt1   = (ushort*)(ws + alloc((size_t)FIN * FIN * 2));
    ushort* Wt2   = (ushort*)(ws + alloc((size_t)CH * FIN * 2));
    float* as1f   = (float*)(ws + alloc((size_t)Nn * H1 * 4));
    float* ad1f   = (float*)(ws + alloc((size_t)Nn * H1 * 4));
    float* as2f   = (float*)(ws + alloc((size_t)Nn * 4));
    float* ad2f   = (float*)(ws + alloc((size_t)Nn * 4));
    float* invl23 = (float*)(ws + alloc((size_t)Nn * 2 * 4));
    int*   offs   = (int*)(ws + alloc((size_t)(Nn + 1) * 4));
    int*   csr    = (int*)(ws + alloc((size_t)ET * 4));
    uint2* pkB    = (uint2*)(ws + alloc((size_t)ET * 8));
    unsigned int* buckets = (unsigned int*)(ws + alloc((size_t)256 * CAP * 4));
    int*   bcnt   = (int*)(ws + alloc(256 * 4));
    int*   flags  = (int*)(ws + alloc(256));
    (void)ws_size; (void)n_in; (void)out_size;

    probe_kernel<<<1, 256, 0, stream>>>((const ushort*)x, (const int*)ei, flags, bcnt);

    // fused prep (convert+transpose) | bucket pass 1
    int PB_conv = (Nn * FIN) / 2048;                       // 8 elem/thread
    int PB_tr   = (FIN * FIN + CH * FIN) / 256;            // 320
    int PB_bkt  = (ET + 4095) / 4096;
    prep_bucket_kernel<<<PB_conv + PB_tr + PB_bkt, 256, 0, stream>>>(
        x, W1, W2, xb, Wt1, Wt2, ei, bcnt, buckets,
        E, ET, Nn, flags, PB_conv, PB_conv + PB_tr);

    // fused: gemm1 (+alpha, planar C) and CSR pass 2
    int nbx = (Nn + 255) / 256;            // 196 row-blocks
    int g1 = nbx * H1;                     // 784 gemm blocks
    gemm1_pass2_kernel<<<g1 + NB, 256, 0, stream>>>(
        xb, Wt1, h1b, Nn, FIN, FIN, as1, ad1, as1f, ad1f,
        flags, g1, nbx, bcnt, buckets, offs, csr, Nn);

    // layer-1 aggregation: pass 0 (inline p, emits pkB+invl23), pass 1 (consumer)
    gat_node1_p0<<<(Nn + 3) / 4, 256, 0, stream>>>(
        csr, offs, as1f, ad1f, h1b, b1, hmidb, pkB, invl23, Nn, flags);
    gat_node1_p1<<<(Nn + 3) / 4, 256, 0, stream>>>(
        pkB, offs, invl23, h1b, b1, hmidb, Nn, flags);

    // layer 2
    gemm2_kernel<<<dim3((Nn + 255) / 256, 1), 256, 0, stream>>>(
        hmidb, Wt2, h2b, Nn, FIN, CH, as2, ad2, as2f, ad2f, flags);
    gat_node2<<<(Nn + 3) / 4, 256, 0, stream>>>(
        csr, offs, as2f, ad2f, h2b, b2, d_out, Nn, flags);
}